// Round 12
// baseline (863.332 us; speedup 1.0000x reference)
//
#include <hip/hip_runtime.h>

// GCNEncoder: 2x GCNConv(64->64) + BatchNorm + ELU + global_mean_pool
// N=50000, E=800000, D=64, G=64. Inputs f32/int32, output f32.
// R23 276.2 -> R27 267.0 (fat kernel hides phist+cnt under mm64) ->
// R28 258.3 (scan2 deleted, part 196 blocks). Launch-graph lever pays;
// kernels are at their floors (R24/R25/R26 falsifications).
// R29: dispatches 11 -> 7, all compute bodies byte-identical:
//  (1) memset deleted: fat kernel gains a zero-range (bnsR/poolR/ticks);
//      cnt -> per-block slots cntR (full overwrite, no zero, no atomics);
//  (2) scan_add2 deleted: part/csr compute global offsets on the fly
//      (LDS scan of the 151-int L2-hot bsum + local-excl hist);
//  (3) bn_final folded into gather_bn's LAST BLOCK (ticket + threadfence +
//      agent-scope loads -- rocPRIM last-block pattern);
//  (4) pool_final folded into gather_pool's last block (also sums cntR).

constexpr int GGRAPHS = 64;
constexpr int EPB = 4096;  // edges per partition block (196 blocks)
constexpr int CNTB = 128;  // blocks for cnt histogram
constexpr int ZBLK = 32;   // zero-fill blocks in fat kernel

// Fat kernel ranges: [0,nblk) phist | [nblk,nblk+CNTB) cnt | +ZBLK zero |
// rest mm64. Bodies identical to standalones.
__global__ void fat_phist_cnt_zero_mm64_kernel(
    const int* __restrict__ dst, const int* __restrict__ batch,
    int* __restrict__ hist, int* __restrict__ cntR, float* __restrict__ zbase,
    const float* __restrict__ X, const float* __restrict__ W,
    float* __restrict__ Y,
    int E, int n, int nblk, int nbuck) {
  __shared__ float Ws[64][64];
  __shared__ float xs[4][64];
  __shared__ int h[256];
  __shared__ int hb[GGRAPHS];
  int t = threadIdx.x;
  int bid = blockIdx.x;
  if (bid < nblk) {
    // ---- phist body ----
    h[t] = 0;
    __syncthreads();
    int e0 = bid * EPB;
    int e1 = e0 + EPB < E ? e0 + EPB : E;
    for (int i = e0 + t; i < e1; i += 256) {
      int d = dst[i];
      if ((unsigned)d < (unsigned)n) atomicAdd(&h[d >> 8], 1);
    }
    __syncthreads();
    if (t < nbuck) hist[t * nblk + bid] = h[t];
  } else if (bid < nblk + CNTB) {
    // ---- cnt body: per-block slot write, no atomics, no pre-zero ----
    int cb = bid - nblk;
    if (t < GGRAPHS) hb[t] = 0;
    __syncthreads();
    for (int i = cb * 256 + t; i < n; i += CNTB * 256) {
      int g = batch[i];
      if ((unsigned)g < (unsigned)GGRAPHS) atomicAdd(&hb[g], 1);
    }
    __syncthreads();
    if (t < GGRAPHS) cntR[cb * 64 + t] = hb[t];
  } else if (bid < nblk + CNTB + ZBLK) {
    // ---- zero range: bnsR(256*128) + poolR(16*4096) + tick(4) floats ----
    int zb = bid - nblk - CNTB;
    float4 z4 = make_float4(0.f, 0.f, 0.f, 0.f);
    int tot4 = (256 * 128 + 16 * 4096 + 4) >> 2;
    float4* d4 = (float4*)zbase;
    for (int i = zb * 256 + t; i < tot4; i += ZBLK * 256) d4[i] = z4;
  } else {
    // ---- mm64 body (4 rows x 64 cols) ----
    int mb = bid - nblk - CNTB - ZBLK;
    for (int i = t; i < 64 * 64; i += 256) Ws[i >> 6][i & 63] = W[i];
    int rr = t >> 6, c = t & 63;
    int row = mb * 4 + rr;
    xs[rr][c] = (row < n) ? X[(size_t)row * 64 + c] : 0.0f;
    __syncthreads();
    float acc = 0.0f;
#pragma unroll
    for (int k = 0; k < 64; ++k) acc = fmaf(xs[rr][k], Ws[k][c], acc);
    if (row < n) Y[(size_t)row * 64 + c] = acc;
  }
}

// scan pass 1: per-256-tile exclusive scan; out[i]=local excl, bsum[b]=tile total.
__global__ void scan1_kernel(const int* __restrict__ in, int* __restrict__ out,
                             int* __restrict__ bsum, int n) {
  __shared__ int tmp[256];
  int t = threadIdx.x;
  int i = blockIdx.x * 256 + t;
  int v = (i < n) ? in[i] : 0;
  tmp[t] = v;
  __syncthreads();
#pragma unroll
  for (int off = 1; off < 256; off <<= 1) {
    int a = (t >= off) ? tmp[t - off] : 0;
    __syncthreads();
    tmp[t] += a;
    __syncthreads();
  }
  if (i < n) out[i] = tmp[t] - v;  // exclusive
  if (t == 255) bsum[blockIdx.x] = tmp[255];
}

// P3: scatter edges into bucket-partitioned array, packed (src<<8)|(dst&255).
// Global offsets computed on the fly: local-excl hist + LDS-scanned bsum.
__global__ void part_kernel(const int* __restrict__ srcp, const int* __restrict__ dstp,
                            const int* __restrict__ hist, const int* __restrict__ bsum,
                            int* __restrict__ part, int E, int n, int nblk, int nbuck,
                            int nbt) {
  __shared__ int tmp[256];
  __shared__ int cur[256];
  int t = threadIdx.x;
  int v = (t < nbt) ? bsum[t] : 0;
  tmp[t] = v;
  __syncthreads();
#pragma unroll
  for (int off = 1; off < 256; off <<= 1) {
    int a = (t >= off) ? tmp[t - off] : 0;
    __syncthreads();
    tmp[t] += a;
    __syncthreads();
  }
  // tmp = inclusive scan of bsum
  if (t < nbuck) {
    int idx = t * nblk + blockIdx.x;
    int tile = idx >> 8;
    int pre = (tile == 0) ? 0 : tmp[tile - 1];
    cur[t] = hist[idx] + pre;
  }
  __syncthreads();
  int e0 = blockIdx.x * EPB;
  int e1 = e0 + EPB < E ? e0 + EPB : E;
  for (int i = e0 + t; i < e1; i += 256) {
    int d = dstp[i];
    if ((unsigned)d >= (unsigned)n) continue;
    int s = srcp[i];
    int pos = atomicAdd(&cur[d >> 8], 1);
    part[pos] = (s << 8) | (d & 255);
  }
}

// P4: one block per bucket (256 nodes). Segment bounds from local-excl hist
// + LDS-scanned bsum. LDS degree -> scan -> rowptr/dinv -> col placement.
__global__ void csr_kernel(const int* __restrict__ part, const int* __restrict__ hist,
                           const int* __restrict__ bsum,
                           int* __restrict__ rowptr, float* __restrict__ dinv,
                           int* __restrict__ col, int n, int nblk, int nbuck,
                           int nbt, int S) {
  __shared__ int tmpb[256];
  __shared__ int degL[256], scn[256], cur[256];
  int t = threadIdx.x;
  int b = blockIdx.x;
  int v = (t < nbt) ? bsum[t] : 0;
  tmpb[t] = v;
  degL[t] = 0;
  cur[t] = 0;
  __syncthreads();
#pragma unroll
  for (int off = 1; off < 256; off <<= 1) {
    int a = (t >= off) ? tmpb[t - off] : 0;
    __syncthreads();
    tmpb[t] += a;
    __syncthreads();
  }
  int bidx = b * nblk;
  int eidx = bidx + nblk;
  int base = hist[bidx] + ((bidx >> 8) ? tmpb[(bidx >> 8) - 1] : 0);
  int total = tmpb[nbt - 1];
  int end = (eidx < S) ? hist[eidx] + ((eidx >> 8) ? tmpb[(eidx >> 8) - 1] : 0) : total;
  for (int i = base + t; i < end; i += 256) atomicAdd(&degL[part[i] & 255], 1);
  __syncthreads();
  int dv = degL[t];
  scn[t] = dv;
  __syncthreads();
#pragma unroll
  for (int off = 1; off < 256; off <<= 1) {
    int a = (t >= off) ? scn[t - off] : 0;
    __syncthreads();
    scn[t] += a;
    __syncthreads();
  }
  int excl = scn[t] - dv;
  int node = (b << 8) + t;
  if (node < n) {
    rowptr[node] = base + excl;
    dinv[node] = rsqrtf((float)dv + 1.0f);
  }
  if (b == nbuck - 1 && t == 0) rowptr[n] = end;
  scn[t] = excl;
  __syncthreads();
  for (int i = base + t; i < end; i += 256) {
    int u = part[i];
    int d = u & 255;
    int k = atomicAdd(&cur[d], 1);
    col[base + scn[d] + k] = u >> 8;
  }
}

// BN affine + ELU on X rows, then @W (known-good 4-row form)
__global__ void bn_elu_mm64_kernel(const float* __restrict__ X, const float* __restrict__ W,
                                   const float* __restrict__ ss, float* __restrict__ Y, int n) {
  __shared__ float Ws[64][64];
  __shared__ float xs[4][64];
  int tid = threadIdx.x;
  for (int i = tid; i < 64 * 64; i += 256) Ws[i >> 6][i & 63] = W[i];
  int rr = tid >> 6, c = tid & 63;
  int row = blockIdx.x * 4 + rr;
  float v = 0.0f;
  if (row < n) {
    v = X[(size_t)row * 64 + c] * ss[c] + ss[64 + c];
    v = v > 0.0f ? v : expm1f(v);
  }
  xs[rr][c] = v;
  __syncthreads();
  float acc = 0.0f;
#pragma unroll
  for (int k = 0; k < 64; ++k) acc = fmaf(xs[rr][k], Ws[k][c], acc);
  if (row < n) Y[(size_t)row * 64 + c] = acc;
}

// Gather core: 1 wave/row, lanes = 4 neighbor-slots x 16 channel-quads.
// R18-proven inner loop: k+=4, one float4 load per iter, unroll 4.
__device__ __forceinline__ float4 gcn_gather_core(
    const int* __restrict__ rowptr, const int* __restrict__ col,
    const float* __restrict__ dinv, const float4* __restrict__ H4,
    int row, int lane, int sub, int cg, bool valid) {
  float4 acc = make_float4(0.f, 0.f, 0.f, 0.f);
  int p0 = 0, p1 = 0;
  if (valid) { p0 = rowptr[row]; p1 = rowptr[row + 1]; }
  for (int base = p0; base < p1; base += 64) {
    int myp = base + lane;
    int j = (myp < p1) ? col[myp] : 0;
    float w = (myp < p1) ? dinv[j] : 0.0f;
    int m = p1 - base;
    m = m < 64 ? m : 64;
#pragma unroll 4
    for (int k = 0; k < m; k += 4) {
      int s = k + sub;               // <= 63 always (k <= 60)
      int jj = __shfl(j, s);
      float ww = __shfl(w, s);       // 0 for tail slots past p1
      float4 hv = H4[(size_t)jj * 16 + cg];
      acc.x = fmaf(hv.x, ww, acc.x);
      acc.y = fmaf(hv.y, ww, acc.y);
      acc.z = fmaf(hv.z, ww, acc.z);
      acc.w = fmaf(hv.w, ww, acc.w);
    }
  }
  acc.x += __shfl_xor(acc.x, 16);
  acc.y += __shfl_xor(acc.y, 16);
  acc.z += __shfl_xor(acc.z, 16);
  acc.w += __shfl_xor(acc.w, 16);
  acc.x += __shfl_xor(acc.x, 32);
  acc.y += __shfl_xor(acc.y, 32);
  acc.z += __shfl_xor(acc.z, 32);
  acc.w += __shfl_xor(acc.w, 32);
  return acc;
}

// gather + BN-stats (256-replica scratch) + LAST-BLOCK bn_final fold.
__global__ void gather_bn_kernel(const int* __restrict__ rowptr, const int* __restrict__ col,
                                 const float* __restrict__ dinv, const float* __restrict__ H,
                                 const float* __restrict__ b, float* __restrict__ OUT,
                                 float* __restrict__ bnsR, int* __restrict__ tick,
                                 const float* __restrict__ gamma, const float* __restrict__ beta,
                                 float* __restrict__ ss, int n) {
  __shared__ float sA[4][64], sB[4][64];
  __shared__ int isLast;
  int wave = threadIdx.x >> 6;
  int lane = threadIdx.x & 63;
  int row = blockIdx.x * 4 + wave;
  bool valid = row < n;
  int sub = lane >> 4;
  int cg = lane & 15;
  const float4* __restrict__ H4 = (const float4*)H;
  float4 acc = gcn_gather_core(rowptr, col, dinv, H4, row, lane, sub, cg, valid);
  float4 o = make_float4(0.f, 0.f, 0.f, 0.f);
  if (valid) {
    float di = dinv[row];
    float d2 = di * di;
    float4 self = H4[(size_t)row * 16 + cg];
    float4 bb = ((const float4*)b)[cg];
    o.x = fmaf(acc.x, di, fmaf(self.x, d2, bb.x));
    o.y = fmaf(acc.y, di, fmaf(self.y, d2, bb.y));
    o.z = fmaf(acc.z, di, fmaf(self.z, d2, bb.z));
    o.w = fmaf(acc.w, di, fmaf(self.w, d2, bb.w));
    if (sub == 0) ((float4*)OUT)[(size_t)row * 16 + cg] = o;
  }
  if (sub == 0) {
    sA[wave][4 * cg + 0] = o.x;
    sA[wave][4 * cg + 1] = o.y;
    sA[wave][4 * cg + 2] = o.z;
    sA[wave][4 * cg + 3] = o.w;
    sB[wave][4 * cg + 0] = o.x * o.x;
    sB[wave][4 * cg + 1] = o.y * o.y;
    sB[wave][4 * cg + 2] = o.z * o.z;
    sB[wave][4 * cg + 3] = o.w * o.w;
  }
  __syncthreads();
  int t = threadIdx.x;
  if (t < 64) {
    float s = sA[0][t] + sA[1][t] + sA[2][t] + sA[3][t];
    float s2 = sB[0][t] + sB[1][t] + sB[2][t] + sB[3][t];
    float* d = bnsR + (size_t)(blockIdx.x & 255) * 128;
    atomicAdd(&d[t], s);
    atomicAdd(&d[64 + t], s2);
  }
  __syncthreads();
  if (t == 0) {
    __threadfence();
    int old = atomicAdd(tick, 1);
    isLast = (old == (int)gridDim.x - 1) ? 1 : 0;
  }
  __syncthreads();
  if (isLast) {
    __threadfence();
    float s = 0.0f;
    if (t < 128) {
      for (int r = 0; r < 256; ++r)
        s += __hip_atomic_load(&bnsR[r * 128 + t], __ATOMIC_RELAXED, __HIP_MEMORY_SCOPE_AGENT);
    }
    float* red = (float*)sA;  // reuse LDS
    if (t < 128) red[t] = s;
    __syncthreads();
    if (t < 64) {
      float inv_n = 1.0f / (float)n;
      float mu = red[t] * inv_n;
      float var = red[64 + t] * inv_n - mu * mu;
      var = fmaxf(var, 0.0f);
      float sc = gamma[t] * rsqrtf(var + 1e-5f);
      ss[t] = sc;
      ss[64 + t] = beta[t] - mu * sc;
    }
  }
}

// gather + pool (16-replica scratch, LDS pre-reduce) + LAST-BLOCK pool_final.
__global__ void gather_pool_kernel(const int* __restrict__ rowptr, const int* __restrict__ col,
                                   const float* __restrict__ dinv, const float* __restrict__ H,
                                   const float* __restrict__ b, float* __restrict__ OUT,
                                   const int* __restrict__ batch, float* __restrict__ poolR,
                                   int* __restrict__ tick, const int* __restrict__ cntR,
                                   float* __restrict__ outG, int n) {
  __shared__ float sO[4][64];
  __shared__ int sG[4];
  __shared__ int isLast;
  __shared__ float cgc[64];
  int wave = threadIdx.x >> 6;
  int lane = threadIdx.x & 63;
  int row = blockIdx.x * 4 + wave;
  bool valid = row < n;
  int sub = lane >> 4;
  int cg = lane & 15;
  const float4* __restrict__ H4 = (const float4*)H;
  float4 acc = gcn_gather_core(rowptr, col, dinv, H4, row, lane, sub, cg, valid);
  float4 o = make_float4(0.f, 0.f, 0.f, 0.f);
  if (valid) {
    float di = dinv[row];
    float d2 = di * di;
    float4 self = H4[(size_t)row * 16 + cg];
    float4 bb = ((const float4*)b)[cg];
    o.x = fmaf(acc.x, di, fmaf(self.x, d2, bb.x));
    o.y = fmaf(acc.y, di, fmaf(self.y, d2, bb.y));
    o.z = fmaf(acc.z, di, fmaf(self.z, d2, bb.z));
    o.w = fmaf(acc.w, di, fmaf(self.w, d2, bb.w));
    if (sub == 0) ((float4*)OUT)[(size_t)row * 16 + cg] = o;
  }
  if (lane == 0) {
    int g = valid ? batch[row] : -1;
    sG[wave] = ((unsigned)g < (unsigned)GGRAPHS) ? g : -1;
  }
  if (sub == 0) {
    sO[wave][4 * cg + 0] = o.x;
    sO[wave][4 * cg + 1] = o.y;
    sO[wave][4 * cg + 2] = o.z;
    sO[wave][4 * cg + 3] = o.w;
  }
  __syncthreads();
  int t = threadIdx.x;
  if (t < 64) {
    float* base = poolR + (size_t)(blockIdx.x & 15) * 4096;
    int g0 = sG[0];
    float s0 = 0.0f;
#pragma unroll
    for (int w = 0; w < 4; ++w) {
      int gw = sG[w];
      if (gw < 0) continue;
      if (gw == g0) s0 += sO[w][t];
      else atomicAdd(&base[gw * 64 + t], sO[w][t]);  // rare: graph boundary
    }
    if (g0 >= 0) atomicAdd(&base[g0 * 64 + t], s0);
  }
  __syncthreads();
  if (t == 0) {
    __threadfence();
    int old = atomicAdd(tick, 1);
    isLast = (old == (int)gridDim.x - 1) ? 1 : 0;
  }
  __syncthreads();
  if (isLast) {
    __threadfence();
    if (t < 64) {
      int c = 0;
      for (int cb = 0; cb < CNTB; ++cb) c += cntR[cb * 64 + t];
      cgc[t] = (float)c;
    }
    __syncthreads();
    for (int idx = t; idx < GGRAPHS * 64; idx += 256) {
      float s = 0.0f;
      for (int r = 0; r < 16; ++r)
        s += __hip_atomic_load(&poolR[r * 4096 + idx], __ATOMIC_RELAXED,
                               __HIP_MEMORY_SCOPE_AGENT);
      outG[idx] = s / fmaxf(cgc[idx >> 6], 1.0f);
    }
  }
}

extern "C" void kernel_launch(void* const* d_in, const int* in_sizes, int n_in,
                              void* d_out, int out_size, void* d_ws, size_t ws_size,
                              hipStream_t stream) {
  const float* x = (const float*)d_in[0];
  const int* ei = (const int*)d_in[1];
  const int* batch = (const int*)d_in[2];
  const float* W1 = (const float*)d_in[3];
  const float* b1 = (const float*)d_in[4];
  const float* gamma = (const float*)d_in[5];
  const float* beta = (const float*)d_in[6];
  const float* W2 = (const float*)d_in[7];
  const float* b2 = (const float*)d_in[8];

  const int n = in_sizes[0] / 64;
  const int E = in_sizes[1] / 2;
  const int* srcp = ei;
  const int* dstp = ei + E;

  int nblkP = (E + EPB - 1) / EPB;    // 196 partition blocks
  int nbuck = (n + 255) >> 8;         // 196 buckets (needs n <= 65536)
  int S = nbuck * nblkP;              // 38416 counters
  int nbt = (S + 255) / 256;          // 151 scan tiles (<= 256)
  int gridRows = (n + 3) / 4;

  float* ws = (float*)d_ws;
  size_t nf = (size_t)n * 64;
  float* bufA = ws;                   // h1, then h2'
  float* bufB = ws + nf;              // pre-BN h
  float* dinv = ws + 2 * nf;          // n floats
  float* ss = dinv + n;               // 128
  int* rowptr = (int*)(ss + 128);     // n+1
  int* col = rowptr + n + 1;          // E
  int* part = col + E;                // E
  int* hist = part + E;               // S+1
  int* bsum = hist + S + 1;           // nbt (<=256)
  // 16B-align the zero region (float4 stores in fat kernel)
  float* bnsR = (float*)(((uintptr_t)(bsum + 256) + 15) & ~(uintptr_t)15);  // 256*128
  float* poolR = bnsR + 256 * 128;    // 16*4096
  int* tick = (int*)(poolR + 16 * 4096);  // 4 ints (tick[0]=bn, tick[1]=pool)
  int* cntR = tick + 4;               // CNTB*64 (full overwrite, no zero)

  float* out = (float*)d_out;  // FLOAT32 output

  int blk = 256;
  int fatGrid = nblkP + CNTB + ZBLK + gridRows;

  fat_phist_cnt_zero_mm64_kernel<<<fatGrid, blk, 0, stream>>>(
      dstp, batch, hist, cntR, bnsR, x, W1, bufA, E, n, nblkP, nbuck);
  scan1_kernel<<<nbt, blk, 0, stream>>>(hist, hist, bsum, S);
  part_kernel<<<nblkP, blk, 0, stream>>>(srcp, dstp, hist, bsum, part, E, n, nblkP,
                                         nbuck, nbt);
  csr_kernel<<<nbuck, blk, 0, stream>>>(part, hist, bsum, rowptr, dinv, col, n, nblkP,
                                        nbuck, nbt, S);

  gather_bn_kernel<<<gridRows, blk, 0, stream>>>(rowptr, col, dinv, bufA, b1, bufB, bnsR,
                                                 &tick[0], gamma, beta, ss, n);
  bn_elu_mm64_kernel<<<gridRows, blk, 0, stream>>>(bufB, W2, ss, bufA, n);
  gather_pool_kernel<<<gridRows, blk, 0, stream>>>(rowptr, col, dinv, bufA, b2, out, batch,
                                                   poolR, &tick[1], cntR, out + nf, n);
}

// Round 13
// 252.548 us; speedup vs baseline: 3.4185x; 3.4185x over previous
//
#include <hip/hip_runtime.h>

// GCNEncoder: 2x GCNConv(64->64) + BatchNorm + ELU + global_mean_pool
// N=50000, E=800000, D=64, G=64. Inputs f32/int32, output f32.
// R27 267.0 -> R28 258.3 BEST (scan2 deleted, part 196 blocks).
// R29 863.3 FAILED: last-block folds = 12.5k serialized same-address
//   ticket RMWs (+threadfence L2 writeback) per gather = +650us. The
//   atomic-chain model now explains R22/R23/R29 -- folds rejected.
// R30 = R28 + R29's two SAFE items only:
//   (1) memset dispatch deleted: fat kernel zero-range (bnsR/poolR);
//       cnt -> per-block cntR slots (no atomics, no pre-zero);
//   (2) scan_add2 deleted: part/csr compute global offsets on the fly
//       (LDS scan of L2-hot bsum + local-excl hist).
//   bn_final / pool_final RESTORED as separate tiny kernels
//   (pool_final sums cntR). Dispatches 11 -> 9.

constexpr int GGRAPHS = 64;
constexpr int EPB = 4096;  // edges per partition block (196 blocks)
constexpr int CNTB = 128;  // blocks for cnt histogram
constexpr int ZBLK = 32;   // zero-fill blocks in fat kernel

// Fat kernel ranges: [0,nblk) phist | [nblk,nblk+CNTB) cnt | +ZBLK zero |
// rest mm64. Bodies identical to standalones.
__global__ void fat_phist_cnt_zero_mm64_kernel(
    const int* __restrict__ dst, const int* __restrict__ batch,
    int* __restrict__ hist, int* __restrict__ cntR, float* __restrict__ zbase,
    const float* __restrict__ X, const float* __restrict__ W,
    float* __restrict__ Y,
    int E, int n, int nblk, int nbuck) {
  __shared__ float Ws[64][64];
  __shared__ float xs[4][64];
  __shared__ int h[256];
  __shared__ int hb[GGRAPHS];
  int t = threadIdx.x;
  int bid = blockIdx.x;
  if (bid < nblk) {
    // ---- phist body ----
    h[t] = 0;
    __syncthreads();
    int e0 = bid * EPB;
    int e1 = e0 + EPB < E ? e0 + EPB : E;
    for (int i = e0 + t; i < e1; i += 256) {
      int d = dst[i];
      if ((unsigned)d < (unsigned)n) atomicAdd(&h[d >> 8], 1);
    }
    __syncthreads();
    if (t < nbuck) hist[t * nblk + bid] = h[t];
  } else if (bid < nblk + CNTB) {
    // ---- cnt body: per-block slot write, no global atomics, no pre-zero ----
    int cb = bid - nblk;
    if (t < GGRAPHS) hb[t] = 0;
    __syncthreads();
    for (int i = cb * 256 + t; i < n; i += CNTB * 256) {
      int g = batch[i];
      if ((unsigned)g < (unsigned)GGRAPHS) atomicAdd(&hb[g], 1);
    }
    __syncthreads();
    if (t < GGRAPHS) cntR[cb * 64 + t] = hb[t];
  } else if (bid < nblk + CNTB + ZBLK) {
    // ---- zero range: bnsR(256*128) + poolR(16*4096) floats ----
    int zb = bid - nblk - CNTB;
    float4 z4 = make_float4(0.f, 0.f, 0.f, 0.f);
    int tot4 = (256 * 128 + 16 * 4096) >> 2;
    float4* d4 = (float4*)zbase;
    for (int i = zb * 256 + t; i < tot4; i += ZBLK * 256) d4[i] = z4;
  } else {
    // ---- mm64 body (4 rows x 64 cols) ----
    int mb = bid - nblk - CNTB - ZBLK;
    for (int i = t; i < 64 * 64; i += 256) Ws[i >> 6][i & 63] = W[i];
    int rr = t >> 6, c = t & 63;
    int row = mb * 4 + rr;
    xs[rr][c] = (row < n) ? X[(size_t)row * 64 + c] : 0.0f;
    __syncthreads();
    float acc = 0.0f;
#pragma unroll
    for (int k = 0; k < 64; ++k) acc = fmaf(xs[rr][k], Ws[k][c], acc);
    if (row < n) Y[(size_t)row * 64 + c] = acc;
  }
}

// scan pass 1: per-256-tile exclusive scan; out[i]=local excl, bsum[b]=tile total.
__global__ void scan1_kernel(const int* __restrict__ in, int* __restrict__ out,
                             int* __restrict__ bsum, int n) {
  __shared__ int tmp[256];
  int t = threadIdx.x;
  int i = blockIdx.x * 256 + t;
  int v = (i < n) ? in[i] : 0;
  tmp[t] = v;
  __syncthreads();
#pragma unroll
  for (int off = 1; off < 256; off <<= 1) {
    int a = (t >= off) ? tmp[t - off] : 0;
    __syncthreads();
    tmp[t] += a;
    __syncthreads();
  }
  if (i < n) out[i] = tmp[t] - v;  // exclusive
  if (t == 255) bsum[blockIdx.x] = tmp[255];
}

// P3: scatter edges into bucket-partitioned array, packed (src<<8)|(dst&255).
// Global offsets computed on the fly: local-excl hist + LDS-scanned bsum.
__global__ void part_kernel(const int* __restrict__ srcp, const int* __restrict__ dstp,
                            const int* __restrict__ hist, const int* __restrict__ bsum,
                            int* __restrict__ part, int E, int n, int nblk, int nbuck,
                            int nbt) {
  __shared__ int tmp[256];
  __shared__ int cur[256];
  int t = threadIdx.x;
  int v = (t < nbt) ? bsum[t] : 0;
  tmp[t] = v;
  __syncthreads();
#pragma unroll
  for (int off = 1; off < 256; off <<= 1) {
    int a = (t >= off) ? tmp[t - off] : 0;
    __syncthreads();
    tmp[t] += a;
    __syncthreads();
  }
  // tmp = inclusive scan of bsum
  if (t < nbuck) {
    int idx = t * nblk + blockIdx.x;
    int tile = idx >> 8;
    int pre = (tile == 0) ? 0 : tmp[tile - 1];
    cur[t] = hist[idx] + pre;
  }
  __syncthreads();
  int e0 = blockIdx.x * EPB;
  int e1 = e0 + EPB < E ? e0 + EPB : E;
  for (int i = e0 + t; i < e1; i += 256) {
    int d = dstp[i];
    if ((unsigned)d >= (unsigned)n) continue;
    int s = srcp[i];
    int pos = atomicAdd(&cur[d >> 8], 1);
    part[pos] = (s << 8) | (d & 255);
  }
}

// P4: one block per bucket (256 nodes). Segment bounds from local-excl hist
// + LDS-scanned bsum. LDS degree -> scan -> rowptr/dinv -> col placement.
__global__ void csr_kernel(const int* __restrict__ part, const int* __restrict__ hist,
                           const int* __restrict__ bsum,
                           int* __restrict__ rowptr, float* __restrict__ dinv,
                           int* __restrict__ col, int n, int nblk, int nbuck,
                           int nbt, int S) {
  __shared__ int tmpb[256];
  __shared__ int degL[256], scn[256], cur[256];
  int t = threadIdx.x;
  int b = blockIdx.x;
  int v = (t < nbt) ? bsum[t] : 0;
  tmpb[t] = v;
  degL[t] = 0;
  cur[t] = 0;
  __syncthreads();
#pragma unroll
  for (int off = 1; off < 256; off <<= 1) {
    int a = (t >= off) ? tmpb[t - off] : 0;
    __syncthreads();
    tmpb[t] += a;
    __syncthreads();
  }
  int bidx = b * nblk;
  int eidx = bidx + nblk;
  int base = hist[bidx] + ((bidx >> 8) ? tmpb[(bidx >> 8) - 1] : 0);
  int total = tmpb[nbt - 1];
  int end = (eidx < S) ? hist[eidx] + ((eidx >> 8) ? tmpb[(eidx >> 8) - 1] : 0) : total;
  for (int i = base + t; i < end; i += 256) atomicAdd(&degL[part[i] & 255], 1);
  __syncthreads();
  int dv = degL[t];
  scn[t] = dv;
  __syncthreads();
#pragma unroll
  for (int off = 1; off < 256; off <<= 1) {
    int a = (t >= off) ? scn[t - off] : 0;
    __syncthreads();
    scn[t] += a;
    __syncthreads();
  }
  int excl = scn[t] - dv;
  int node = (b << 8) + t;
  if (node < n) {
    rowptr[node] = base + excl;
    dinv[node] = rsqrtf((float)dv + 1.0f);
  }
  if (b == nbuck - 1 && t == 0) rowptr[n] = end;
  scn[t] = excl;
  __syncthreads();
  for (int i = base + t; i < end; i += 256) {
    int u = part[i];
    int d = u & 255;
    int k = atomicAdd(&cur[d], 1);
    col[base + scn[d] + k] = u >> 8;
  }
}

// BN affine + ELU on X rows, then @W (known-good 4-row form)
__global__ void bn_elu_mm64_kernel(const float* __restrict__ X, const float* __restrict__ W,
                                   const float* __restrict__ ss, float* __restrict__ Y, int n) {
  __shared__ float Ws[64][64];
  __shared__ float xs[4][64];
  int tid = threadIdx.x;
  for (int i = tid; i < 64 * 64; i += 256) Ws[i >> 6][i & 63] = W[i];
  int rr = tid >> 6, c = tid & 63;
  int row = blockIdx.x * 4 + rr;
  float v = 0.0f;
  if (row < n) {
    v = X[(size_t)row * 64 + c] * ss[c] + ss[64 + c];
    v = v > 0.0f ? v : expm1f(v);
  }
  xs[rr][c] = v;
  __syncthreads();
  float acc = 0.0f;
#pragma unroll
  for (int k = 0; k < 64; ++k) acc = fmaf(xs[rr][k], Ws[k][c], acc);
  if (row < n) Y[(size_t)row * 64 + c] = acc;
}

// Gather core: 1 wave/row, lanes = 4 neighbor-slots x 16 channel-quads.
// R18-proven inner loop: k+=4, one float4 load per iter, unroll 4.
__device__ __forceinline__ float4 gcn_gather_core(
    const int* __restrict__ rowptr, const int* __restrict__ col,
    const float* __restrict__ dinv, const float4* __restrict__ H4,
    int row, int lane, int sub, int cg, bool valid) {
  float4 acc = make_float4(0.f, 0.f, 0.f, 0.f);
  int p0 = 0, p1 = 0;
  if (valid) { p0 = rowptr[row]; p1 = rowptr[row + 1]; }
  for (int base = p0; base < p1; base += 64) {
    int myp = base + lane;
    int j = (myp < p1) ? col[myp] : 0;
    float w = (myp < p1) ? dinv[j] : 0.0f;
    int m = p1 - base;
    m = m < 64 ? m : 64;
#pragma unroll 4
    for (int k = 0; k < m; k += 4) {
      int s = k + sub;               // <= 63 always (k <= 60)
      int jj = __shfl(j, s);
      float ww = __shfl(w, s);       // 0 for tail slots past p1
      float4 hv = H4[(size_t)jj * 16 + cg];
      acc.x = fmaf(hv.x, ww, acc.x);
      acc.y = fmaf(hv.y, ww, acc.y);
      acc.z = fmaf(hv.z, ww, acc.z);
      acc.w = fmaf(hv.w, ww, acc.w);
    }
  }
  acc.x += __shfl_xor(acc.x, 16);
  acc.y += __shfl_xor(acc.y, 16);
  acc.z += __shfl_xor(acc.z, 16);
  acc.w += __shfl_xor(acc.w, 16);
  acc.x += __shfl_xor(acc.x, 32);
  acc.y += __shfl_xor(acc.y, 32);
  acc.z += __shfl_xor(acc.z, 32);
  acc.w += __shfl_xor(acc.w, 32);
  return acc;
}

// gather + BN-stat accumulation (256-replica scratch bnsR[256][128]).
__global__ void gather_bn_kernel(const int* __restrict__ rowptr, const int* __restrict__ col,
                                 const float* __restrict__ dinv, const float* __restrict__ H,
                                 const float* __restrict__ b, float* __restrict__ OUT,
                                 float* __restrict__ bnsR, int n) {
  int wave = threadIdx.x >> 6;
  int lane = threadIdx.x & 63;
  int row = blockIdx.x * 4 + wave;
  bool valid = row < n;
  int sub = lane >> 4;
  int cg = lane & 15;
  const float4* __restrict__ H4 = (const float4*)H;
  float4 acc = gcn_gather_core(rowptr, col, dinv, H4, row, lane, sub, cg, valid);
  float4 o = make_float4(0.f, 0.f, 0.f, 0.f);
  if (valid) {
    float di = dinv[row];
    float d2 = di * di;
    float4 self = H4[(size_t)row * 16 + cg];
    float4 bb = ((const float4*)b)[cg];
    o.x = fmaf(acc.x, di, fmaf(self.x, d2, bb.x));
    o.y = fmaf(acc.y, di, fmaf(self.y, d2, bb.y));
    o.z = fmaf(acc.z, di, fmaf(self.z, d2, bb.z));
    o.w = fmaf(acc.w, di, fmaf(self.w, d2, bb.w));
    if (sub == 0) ((float4*)OUT)[(size_t)row * 16 + cg] = o;
  }
  __shared__ float sA[4][64], sB[4][64];
  if (sub == 0) {
    sA[wave][4 * cg + 0] = o.x;
    sA[wave][4 * cg + 1] = o.y;
    sA[wave][4 * cg + 2] = o.z;
    sA[wave][4 * cg + 3] = o.w;
    sB[wave][4 * cg + 0] = o.x * o.x;
    sB[wave][4 * cg + 1] = o.y * o.y;
    sB[wave][4 * cg + 2] = o.z * o.z;
    sB[wave][4 * cg + 3] = o.w * o.w;
  }
  __syncthreads();
  int t = threadIdx.x;
  if (t < 64) {
    float s = sA[0][t] + sA[1][t] + sA[2][t] + sA[3][t];
    float s2 = sB[0][t] + sB[1][t] + sB[2][t] + sB[3][t];
    float* d = bnsR + (size_t)(blockIdx.x & 255) * 128;
    atomicAdd(&d[t], s);
    atomicAdd(&d[64 + t], s2);
  }
}

// gather + pool accumulation: LDS pre-reduce the block's 4 (sorted) rows,
// then 64 atomics/block to one of 16 replicas (chains ~12).
__global__ void gather_pool_kernel(const int* __restrict__ rowptr, const int* __restrict__ col,
                                   const float* __restrict__ dinv, const float* __restrict__ H,
                                   const float* __restrict__ b, float* __restrict__ OUT,
                                   const int* __restrict__ batch, float* __restrict__ poolR,
                                   int n) {
  int wave = threadIdx.x >> 6;
  int lane = threadIdx.x & 63;
  int row = blockIdx.x * 4 + wave;
  bool valid = row < n;
  int sub = lane >> 4;
  int cg = lane & 15;
  const float4* __restrict__ H4 = (const float4*)H;
  float4 acc = gcn_gather_core(rowptr, col, dinv, H4, row, lane, sub, cg, valid);
  float4 o = make_float4(0.f, 0.f, 0.f, 0.f);
  __shared__ float sO[4][64];
  __shared__ int sG[4];
  if (valid) {
    float di = dinv[row];
    float d2 = di * di;
    float4 self = H4[(size_t)row * 16 + cg];
    float4 bb = ((const float4*)b)[cg];
    o.x = fmaf(acc.x, di, fmaf(self.x, d2, bb.x));
    o.y = fmaf(acc.y, di, fmaf(self.y, d2, bb.y));
    o.z = fmaf(acc.z, di, fmaf(self.z, d2, bb.z));
    o.w = fmaf(acc.w, di, fmaf(self.w, d2, bb.w));
    if (sub == 0) ((float4*)OUT)[(size_t)row * 16 + cg] = o;
  }
  if (lane == 0) {
    int g = valid ? batch[row] : -1;
    sG[wave] = ((unsigned)g < (unsigned)GGRAPHS) ? g : -1;
  }
  if (sub == 0) {
    sO[wave][4 * cg + 0] = o.x;
    sO[wave][4 * cg + 1] = o.y;
    sO[wave][4 * cg + 2] = o.z;
    sO[wave][4 * cg + 3] = o.w;
  }
  __syncthreads();
  int t = threadIdx.x;
  if (t < 64) {
    float* base = poolR + (size_t)(blockIdx.x & 15) * 4096;
    int g0 = sG[0];
    float s0 = 0.0f;
#pragma unroll
    for (int w = 0; w < 4; ++w) {
      int gw = sG[w];
      if (gw < 0) continue;
      if (gw == g0) s0 += sO[w][t];
      else atomicAdd(&base[gw * 64 + t], sO[w][t]);  // rare: graph boundary
    }
    if (g0 >= 0) atomicAdd(&base[g0 * 64 + t], s0);
  }
}

// reduce 256 BN replicas -> scale/shift
__global__ void bn_final_kernel(const float* __restrict__ bnsR, const float* __restrict__ gamma,
                                const float* __restrict__ beta, float* __restrict__ ss, int n) {
  __shared__ float red[128];
  int t = threadIdx.x;  // 128 threads
  float s = 0.0f;
  for (int r = 0; r < 256; ++r) s += bnsR[r * 128 + t];
  red[t] = s;
  __syncthreads();
  if (t < 64) {
    float inv_n = 1.0f / (float)n;
    float mu = red[t] * inv_n;
    float var = red[64 + t] * inv_n - mu * mu;
    var = fmaxf(var, 0.0f);
    float sc = gamma[t] * rsqrtf(var + 1e-5f);
    ss[t] = sc;
    ss[64 + t] = beta[t] - mu * sc;
  }
}

// reduce 16 pool replicas + CNTB cnt slots, divide by count
__global__ void pool_final_kernel(const float* __restrict__ poolR, const int* __restrict__ cntR,
                                  float* __restrict__ out) {
  __shared__ float cgc[64];
  int t = threadIdx.x;
  if (t < 64) {
    int g = (blockIdx.x * 256 + t) >> 6;  // not per-thread g; compute per block
  }
  // per-block graph-count reduce: each block covers 4 graphs (256 ch)
  int idx = blockIdx.x * 256 + t;  // 4096 total
  int g = idx >> 6;
  if (t < 4) {
    int gg = (blockIdx.x * 256) / 64 + t;  // 4 graphs per block
    int c = 0;
    for (int cb = 0; cb < CNTB; ++cb) c += cntR[cb * 64 + gg];
    cgc[t] = (float)c;
  }
  __syncthreads();
  float s = 0.0f;
  for (int r = 0; r < 16; ++r) s += poolR[r * 4096 + idx];
  out[idx] = s / fmaxf(cgc[(t >> 6)], 1.0f);
}

extern "C" void kernel_launch(void* const* d_in, const int* in_sizes, int n_in,
                              void* d_out, int out_size, void* d_ws, size_t ws_size,
                              hipStream_t stream) {
  const float* x = (const float*)d_in[0];
  const int* ei = (const int*)d_in[1];
  const int* batch = (const int*)d_in[2];
  const float* W1 = (const float*)d_in[3];
  const float* b1 = (const float*)d_in[4];
  const float* gamma = (const float*)d_in[5];
  const float* beta = (const float*)d_in[6];
  const float* W2 = (const float*)d_in[7];
  const float* b2 = (const float*)d_in[8];

  const int n = in_sizes[0] / 64;
  const int E = in_sizes[1] / 2;
  const int* srcp = ei;
  const int* dstp = ei + E;

  int nblkP = (E + EPB - 1) / EPB;    // 196 partition blocks
  int nbuck = (n + 255) >> 8;         // 196 buckets (needs n <= 65536)
  int S = nbuck * nblkP;              // 38416 counters
  int nbt = (S + 255) / 256;          // 151 scan tiles (<= 256)
  int gridRows = (n + 3) / 4;

  float* ws = (float*)d_ws;
  size_t nf = (size_t)n * 64;
  float* bufA = ws;                   // h1, then h2'
  float* bufB = ws + nf;              // pre-BN h
  float* dinv = ws + 2 * nf;          // n floats
  float* ss = dinv + n;               // 128
  int* rowptr = (int*)(ss + 128);     // n+1
  int* col = rowptr + n + 1;          // E
  int* part = col + E;                // E
  int* hist = part + E;               // S+1
  int* bsum = hist + S + 1;           // nbt (<=256)
  // 16B-align the zero region (float4 stores in fat kernel)
  float* bnsR = (float*)(((uintptr_t)(bsum + 256) + 15) & ~(uintptr_t)15);  // 256*128
  float* poolR = bnsR + 256 * 128;    // 16*4096
  int* cntR = (int*)(poolR + 16 * 4096);  // CNTB*64 (full overwrite, no zero)

  float* out = (float*)d_out;  // FLOAT32 output

  int blk = 256;
  int fatGrid = nblkP + CNTB + ZBLK + gridRows;

  fat_phist_cnt_zero_mm64_kernel<<<fatGrid, blk, 0, stream>>>(
      dstp, batch, hist, cntR, bnsR, x, W1, bufA, E, n, nblkP, nbuck);
  scan1_kernel<<<nbt, blk, 0, stream>>>(hist, hist, bsum, S);
  part_kernel<<<nblkP, blk, 0, stream>>>(srcp, dstp, hist, bsum, part, E, n, nblkP,
                                         nbuck, nbt);
  csr_kernel<<<nbuck, blk, 0, stream>>>(part, hist, bsum, rowptr, dinv, col, n, nblkP,
                                        nbuck, nbt, S);

  gather_bn_kernel<<<gridRows, blk, 0, stream>>>(rowptr, col, dinv, bufA, b1, bufB, bnsR, n);
  bn_final_kernel<<<1, 128, 0, stream>>>(bnsR, gamma, beta, ss, n);
  bn_elu_mm64_kernel<<<gridRows, blk, 0, stream>>>(bufB, W2, ss, bufA, n);
  gather_pool_kernel<<<gridRows, blk, 0, stream>>>(rowptr, col, dinv, bufA, b2, out, batch,
                                                   poolR, n);
  pool_final_kernel<<<16, blk, 0, stream>>>(poolR, cntR, out + nf);
}

// Round 14
// 240.652 us; speedup vs baseline: 3.5875x; 1.0494x over previous
//
#include <hip/hip_runtime.h>

// GCNEncoder: 2x GCNConv(64->64) + BatchNorm + ELU + global_mean_pool
// N=50000, E=800000, D=64, G=64. Inputs f32/int32, output f32.
// R27 267.0 -> R28 258.3 -> R30 252.5 BEST (memset+scan_add deleted;
//   finals kept as tiny kernels -- R29's ticket folds cost +650us).
// R31: mm64's 12.5k blocks currently all drain inside dispatch #1 before
//   the serial CSR chain (scan1->part->csr) can start, though that chain
//   depends only on phist. Distribute mm64 as fat ranges across ALL FOUR
//   preproc dispatches (body blocks first, mm64 chunk behind): chain cost
//   goes from max(phist,mm64)+scan1+part+csr to ~Sum max(body_i,chunk_i).
//   All compute bodies byte-identical to R30. Dispatches stay 9.

constexpr int GGRAPHS = 64;
constexpr int EPB = 4096;  // edges per partition block (196 blocks)
constexpr int CNTB = 128;  // blocks for cnt histogram
constexpr int ZBLK = 32;   // zero-fill blocks in fat kernel A

// ---- shared mm64 body (4 rows x 64 cols, known-good) ----
__device__ __forceinline__ void mm64_body(
    const float* __restrict__ X, const float* __restrict__ W,
    float* __restrict__ Y, float (*Ws)[64], float (*xs)[64],
    int mb, int n, int t) {
  for (int i = t; i < 64 * 64; i += 256) Ws[i >> 6][i & 63] = W[i];
  int rr = t >> 6, c = t & 63;
  int row = mb * 4 + rr;
  xs[rr][c] = (row < n) ? X[(size_t)row * 64 + c] : 0.0f;
  __syncthreads();
  float acc = 0.0f;
#pragma unroll
  for (int k = 0; k < 64; ++k) acc = fmaf(xs[rr][k], Ws[k][c], acc);
  if (row < n) Y[(size_t)row * 64 + c] = acc;
}

// Fat A: [0,nblk) phist | +CNTB cnt | +ZBLK zero | rest mm64 chunk [c0,..).
__global__ void fatA_kernel(
    const int* __restrict__ dst, const int* __restrict__ batch,
    int* __restrict__ hist, int* __restrict__ cntR, float* __restrict__ zbase,
    const float* __restrict__ X, const float* __restrict__ W,
    float* __restrict__ Y, int E, int n, int nblk, int nbuck, int c0) {
  __shared__ float Ws[64][64];
  __shared__ float xs[4][64];
  __shared__ int h[256];
  __shared__ int hb[GGRAPHS];
  int t = threadIdx.x;
  int bid = blockIdx.x;
  if (bid < nblk) {
    h[t] = 0;
    __syncthreads();
    int e0 = bid * EPB;
    int e1 = e0 + EPB < E ? e0 + EPB : E;
    for (int i = e0 + t; i < e1; i += 256) {
      int d = dst[i];
      if ((unsigned)d < (unsigned)n) atomicAdd(&h[d >> 8], 1);
    }
    __syncthreads();
    if (t < nbuck) hist[t * nblk + bid] = h[t];
  } else if (bid < nblk + CNTB) {
    int cb = bid - nblk;
    if (t < GGRAPHS) hb[t] = 0;
    __syncthreads();
    for (int i = cb * 256 + t; i < n; i += CNTB * 256) {
      int g = batch[i];
      if ((unsigned)g < (unsigned)GGRAPHS) atomicAdd(&hb[g], 1);
    }
    __syncthreads();
    if (t < GGRAPHS) cntR[cb * 64 + t] = hb[t];
  } else if (bid < nblk + CNTB + ZBLK) {
    int zb = bid - nblk - CNTB;
    float4 z4 = make_float4(0.f, 0.f, 0.f, 0.f);
    int tot4 = (256 * 128 + 16 * 4096) >> 2;
    float4* d4 = (float4*)zbase;
    for (int i = zb * 256 + t; i < tot4; i += ZBLK * 256) d4[i] = z4;
  } else {
    mm64_body(X, W, Y, Ws, xs, c0 + (bid - nblk - CNTB - ZBLK), n, t);
  }
}

// Fat B: [0,nbt) scan1 | rest mm64 chunk.
__global__ void fatB_kernel(const int* __restrict__ in, int* __restrict__ outp,
                            int* __restrict__ bsum,
                            const float* __restrict__ X, const float* __restrict__ W,
                            float* __restrict__ Y, int S, int n, int nbt, int c0) {
  __shared__ float Ws[64][64];
  __shared__ float xs[4][64];
  __shared__ int tmp[256];
  int t = threadIdx.x;
  int bid = blockIdx.x;
  if (bid < nbt) {
    int i = bid * 256 + t;
    int v = (i < S) ? in[i] : 0;
    tmp[t] = v;
    __syncthreads();
#pragma unroll
    for (int off = 1; off < 256; off <<= 1) {
      int a = (t >= off) ? tmp[t - off] : 0;
      __syncthreads();
      tmp[t] += a;
      __syncthreads();
    }
    if (i < S) outp[i] = tmp[t] - v;  // exclusive
    if (t == 255) bsum[bid] = tmp[255];
  } else {
    mm64_body(X, W, Y, Ws, xs, c0 + (bid - nbt), n, t);
  }
}

// Fat C: [0,nblk) part | rest mm64 chunk.
__global__ void fatC_kernel(const int* __restrict__ srcp, const int* __restrict__ dstp,
                            const int* __restrict__ hist, const int* __restrict__ bsum,
                            int* __restrict__ part,
                            const float* __restrict__ X, const float* __restrict__ W,
                            float* __restrict__ Y,
                            int E, int n, int nblk, int nbuck, int nbt, int c0) {
  __shared__ float Ws[64][64];
  __shared__ float xs[4][64];
  __shared__ int tmp[256];
  __shared__ int cur[256];
  int t = threadIdx.x;
  int bid = blockIdx.x;
  if (bid < nblk) {
    int v = (t < nbt) ? bsum[t] : 0;
    tmp[t] = v;
    __syncthreads();
#pragma unroll
    for (int off = 1; off < 256; off <<= 1) {
      int a = (t >= off) ? tmp[t - off] : 0;
      __syncthreads();
      tmp[t] += a;
      __syncthreads();
    }
    if (t < nbuck) {
      int idx = t * nblk + bid;
      int tile = idx >> 8;
      int pre = (tile == 0) ? 0 : tmp[tile - 1];
      cur[t] = hist[idx] + pre;
    }
    __syncthreads();
    int e0 = bid * EPB;
    int e1 = e0 + EPB < E ? e0 + EPB : E;
    for (int i = e0 + t; i < e1; i += 256) {
      int d = dstp[i];
      if ((unsigned)d >= (unsigned)n) continue;
      int s = srcp[i];
      int pos = atomicAdd(&cur[d >> 8], 1);
      part[pos] = (s << 8) | (d & 255);
    }
  } else {
    mm64_body(X, W, Y, Ws, xs, c0 + (bid - nblk), n, t);
  }
}

// Fat D: [0,nbuck) csr | rest mm64 chunk.
__global__ void fatD_kernel(const int* __restrict__ part, const int* __restrict__ hist,
                            const int* __restrict__ bsum,
                            int* __restrict__ rowptr, float* __restrict__ dinv,
                            int* __restrict__ col,
                            const float* __restrict__ X, const float* __restrict__ W,
                            float* __restrict__ Y,
                            int n, int nblk, int nbuck, int nbt, int S, int c0) {
  __shared__ float Ws[64][64];
  __shared__ float xs[4][64];
  __shared__ int tmpb[256];
  __shared__ int degL[256], scn[256], cur[256];
  int t = threadIdx.x;
  int b = blockIdx.x;
  if (b < nbuck) {
    int v = (t < nbt) ? bsum[t] : 0;
    tmpb[t] = v;
    degL[t] = 0;
    cur[t] = 0;
    __syncthreads();
#pragma unroll
    for (int off = 1; off < 256; off <<= 1) {
      int a = (t >= off) ? tmpb[t - off] : 0;
      __syncthreads();
      tmpb[t] += a;
      __syncthreads();
    }
    int bidx = b * nblk;
    int eidx = bidx + nblk;
    int base = hist[bidx] + ((bidx >> 8) ? tmpb[(bidx >> 8) - 1] : 0);
    int total = tmpb[nbt - 1];
    int end = (eidx < S) ? hist[eidx] + ((eidx >> 8) ? tmpb[(eidx >> 8) - 1] : 0) : total;
    for (int i = base + t; i < end; i += 256) atomicAdd(&degL[part[i] & 255], 1);
    __syncthreads();
    int dv = degL[t];
    scn[t] = dv;
    __syncthreads();
#pragma unroll
    for (int off = 1; off < 256; off <<= 1) {
      int a = (t >= off) ? scn[t - off] : 0;
      __syncthreads();
      scn[t] += a;
      __syncthreads();
    }
    int excl = scn[t] - dv;
    int node = (b << 8) + t;
    if (node < n) {
      rowptr[node] = base + excl;
      dinv[node] = rsqrtf((float)dv + 1.0f);
    }
    if (b == nbuck - 1 && t == 0) rowptr[n] = end;
    scn[t] = excl;
    __syncthreads();
    for (int i = base + t; i < end; i += 256) {
      int u = part[i];
      int d = u & 255;
      int k = atomicAdd(&cur[d], 1);
      col[base + scn[d] + k] = u >> 8;
    }
  } else {
    mm64_body(X, W, Y, Ws, xs, c0 + (b - nbuck), n, t);
  }
}

// BN affine + ELU on X rows, then @W (known-good 4-row form)
__global__ void bn_elu_mm64_kernel(const float* __restrict__ X, const float* __restrict__ W,
                                   const float* __restrict__ ss, float* __restrict__ Y, int n) {
  __shared__ float Ws[64][64];
  __shared__ float xs[4][64];
  int tid = threadIdx.x;
  for (int i = tid; i < 64 * 64; i += 256) Ws[i >> 6][i & 63] = W[i];
  int rr = tid >> 6, c = tid & 63;
  int row = blockIdx.x * 4 + rr;
  float v = 0.0f;
  if (row < n) {
    v = X[(size_t)row * 64 + c] * ss[c] + ss[64 + c];
    v = v > 0.0f ? v : expm1f(v);
  }
  xs[rr][c] = v;
  __syncthreads();
  float acc = 0.0f;
#pragma unroll
  for (int k = 0; k < 64; ++k) acc = fmaf(xs[rr][k], Ws[k][c], acc);
  if (row < n) Y[(size_t)row * 64 + c] = acc;
}

// Gather core: 1 wave/row, lanes = 4 neighbor-slots x 16 channel-quads.
// R18-proven inner loop: k+=4, one float4 load per iter, unroll 4.
__device__ __forceinline__ float4 gcn_gather_core(
    const int* __restrict__ rowptr, const int* __restrict__ col,
    const float* __restrict__ dinv, const float4* __restrict__ H4,
    int row, int lane, int sub, int cg, bool valid) {
  float4 acc = make_float4(0.f, 0.f, 0.f, 0.f);
  int p0 = 0, p1 = 0;
  if (valid) { p0 = rowptr[row]; p1 = rowptr[row + 1]; }
  for (int base = p0; base < p1; base += 64) {
    int myp = base + lane;
    int j = (myp < p1) ? col[myp] : 0;
    float w = (myp < p1) ? dinv[j] : 0.0f;
    int m = p1 - base;
    m = m < 64 ? m : 64;
#pragma unroll 4
    for (int k = 0; k < m; k += 4) {
      int s = k + sub;               // <= 63 always (k <= 60)
      int jj = __shfl(j, s);
      float ww = __shfl(w, s);       // 0 for tail slots past p1
      float4 hv = H4[(size_t)jj * 16 + cg];
      acc.x = fmaf(hv.x, ww, acc.x);
      acc.y = fmaf(hv.y, ww, acc.y);
      acc.z = fmaf(hv.z, ww, acc.z);
      acc.w = fmaf(hv.w, ww, acc.w);
    }
  }
  acc.x += __shfl_xor(acc.x, 16);
  acc.y += __shfl_xor(acc.y, 16);
  acc.z += __shfl_xor(acc.z, 16);
  acc.w += __shfl_xor(acc.w, 16);
  acc.x += __shfl_xor(acc.x, 32);
  acc.y += __shfl_xor(acc.y, 32);
  acc.z += __shfl_xor(acc.z, 32);
  acc.w += __shfl_xor(acc.w, 32);
  return acc;
}

// gather + BN-stat accumulation (256-replica scratch bnsR[256][128]).
__global__ void gather_bn_kernel(const int* __restrict__ rowptr, const int* __restrict__ col,
                                 const float* __restrict__ dinv, const float* __restrict__ H,
                                 const float* __restrict__ b, float* __restrict__ OUT,
                                 float* __restrict__ bnsR, int n) {
  int wave = threadIdx.x >> 6;
  int lane = threadIdx.x & 63;
  int row = blockIdx.x * 4 + wave;
  bool valid = row < n;
  int sub = lane >> 4;
  int cg = lane & 15;
  const float4* __restrict__ H4 = (const float4*)H;
  float4 acc = gcn_gather_core(rowptr, col, dinv, H4, row, lane, sub, cg, valid);
  float4 o = make_float4(0.f, 0.f, 0.f, 0.f);
  if (valid) {
    float di = dinv[row];
    float d2 = di * di;
    float4 self = H4[(size_t)row * 16 + cg];
    float4 bb = ((const float4*)b)[cg];
    o.x = fmaf(acc.x, di, fmaf(self.x, d2, bb.x));
    o.y = fmaf(acc.y, di, fmaf(self.y, d2, bb.y));
    o.z = fmaf(acc.z, di, fmaf(self.z, d2, bb.z));
    o.w = fmaf(acc.w, di, fmaf(self.w, d2, bb.w));
    if (sub == 0) ((float4*)OUT)[(size_t)row * 16 + cg] = o;
  }
  __shared__ float sA[4][64], sB[4][64];
  if (sub == 0) {
    sA[wave][4 * cg + 0] = o.x;
    sA[wave][4 * cg + 1] = o.y;
    sA[wave][4 * cg + 2] = o.z;
    sA[wave][4 * cg + 3] = o.w;
    sB[wave][4 * cg + 0] = o.x * o.x;
    sB[wave][4 * cg + 1] = o.y * o.y;
    sB[wave][4 * cg + 2] = o.z * o.z;
    sB[wave][4 * cg + 3] = o.w * o.w;
  }
  __syncthreads();
  int t = threadIdx.x;
  if (t < 64) {
    float s = sA[0][t] + sA[1][t] + sA[2][t] + sA[3][t];
    float s2 = sB[0][t] + sB[1][t] + sB[2][t] + sB[3][t];
    float* d = bnsR + (size_t)(blockIdx.x & 255) * 128;
    atomicAdd(&d[t], s);
    atomicAdd(&d[64 + t], s2);
  }
}

// gather + pool accumulation: LDS pre-reduce the block's 4 (sorted) rows,
// then 64 atomics/block to one of 16 replicas (chains ~12).
__global__ void gather_pool_kernel(const int* __restrict__ rowptr, const int* __restrict__ col,
                                   const float* __restrict__ dinv, const float* __restrict__ H,
                                   const float* __restrict__ b, float* __restrict__ OUT,
                                   const int* __restrict__ batch, float* __restrict__ poolR,
                                   int n) {
  int wave = threadIdx.x >> 6;
  int lane = threadIdx.x & 63;
  int row = blockIdx.x * 4 + wave;
  bool valid = row < n;
  int sub = lane >> 4;
  int cg = lane & 15;
  const float4* __restrict__ H4 = (const float4*)H;
  float4 acc = gcn_gather_core(rowptr, col, dinv, H4, row, lane, sub, cg, valid);
  float4 o = make_float4(0.f, 0.f, 0.f, 0.f);
  __shared__ float sO[4][64];
  __shared__ int sG[4];
  if (valid) {
    float di = dinv[row];
    float d2 = di * di;
    float4 self = H4[(size_t)row * 16 + cg];
    float4 bb = ((const float4*)b)[cg];
    o.x = fmaf(acc.x, di, fmaf(self.x, d2, bb.x));
    o.y = fmaf(acc.y, di, fmaf(self.y, d2, bb.y));
    o.z = fmaf(acc.z, di, fmaf(self.z, d2, bb.z));
    o.w = fmaf(acc.w, di, fmaf(self.w, d2, bb.w));
    if (sub == 0) ((float4*)OUT)[(size_t)row * 16 + cg] = o;
  }
  if (lane == 0) {
    int g = valid ? batch[row] : -1;
    sG[wave] = ((unsigned)g < (unsigned)GGRAPHS) ? g : -1;
  }
  if (sub == 0) {
    sO[wave][4 * cg + 0] = o.x;
    sO[wave][4 * cg + 1] = o.y;
    sO[wave][4 * cg + 2] = o.z;
    sO[wave][4 * cg + 3] = o.w;
  }
  __syncthreads();
  int t = threadIdx.x;
  if (t < 64) {
    float* base = poolR + (size_t)(blockIdx.x & 15) * 4096;
    int g0 = sG[0];
    float s0 = 0.0f;
#pragma unroll
    for (int w = 0; w < 4; ++w) {
      int gw = sG[w];
      if (gw < 0) continue;
      if (gw == g0) s0 += sO[w][t];
      else atomicAdd(&base[gw * 64 + t], sO[w][t]);  // rare: graph boundary
    }
    if (g0 >= 0) atomicAdd(&base[g0 * 64 + t], s0);
  }
}

// reduce 256 BN replicas -> scale/shift
__global__ void bn_final_kernel(const float* __restrict__ bnsR, const float* __restrict__ gamma,
                                const float* __restrict__ beta, float* __restrict__ ss, int n) {
  __shared__ float red[128];
  int t = threadIdx.x;  // 128 threads
  float s = 0.0f;
  for (int r = 0; r < 256; ++r) s += bnsR[r * 128 + t];
  red[t] = s;
  __syncthreads();
  if (t < 64) {
    float inv_n = 1.0f / (float)n;
    float mu = red[t] * inv_n;
    float var = red[64 + t] * inv_n - mu * mu;
    var = fmaxf(var, 0.0f);
    float sc = gamma[t] * rsqrtf(var + 1e-5f);
    ss[t] = sc;
    ss[64 + t] = beta[t] - mu * sc;
  }
}

// reduce 16 pool replicas + CNTB cnt slots, divide by count
__global__ void pool_final_kernel(const float* __restrict__ poolR, const int* __restrict__ cntR,
                                  float* __restrict__ out) {
  __shared__ float cgc[64];
  int t = threadIdx.x;
  int idx = blockIdx.x * 256 + t;  // 4096 total
  if (t < 4) {
    int gg = (blockIdx.x * 256) / 64 + t;  // 4 graphs per block
    int c = 0;
    for (int cb = 0; cb < CNTB; ++cb) c += cntR[cb * 64 + gg];
    cgc[t] = (float)c;
  }
  __syncthreads();
  float s = 0.0f;
  for (int r = 0; r < 16; ++r) s += poolR[r * 4096 + idx];
  out[idx] = s / fmaxf(cgc[(t >> 6)], 1.0f);
}

extern "C" void kernel_launch(void* const* d_in, const int* in_sizes, int n_in,
                              void* d_out, int out_size, void* d_ws, size_t ws_size,
                              hipStream_t stream) {
  const float* x = (const float*)d_in[0];
  const int* ei = (const int*)d_in[1];
  const int* batch = (const int*)d_in[2];
  const float* W1 = (const float*)d_in[3];
  const float* b1 = (const float*)d_in[4];
  const float* gamma = (const float*)d_in[5];
  const float* beta = (const float*)d_in[6];
  const float* W2 = (const float*)d_in[7];
  const float* b2 = (const float*)d_in[8];

  const int n = in_sizes[0] / 64;
  const int E = in_sizes[1] / 2;
  const int* srcp = ei;
  const int* dstp = ei + E;

  int nblkP = (E + EPB - 1) / EPB;    // 196 partition blocks
  int nbuck = (n + 255) >> 8;         // 196 buckets (needs n <= 65536)
  int S = nbuck * nblkP;              // 38416 counters
  int nbt = (S + 255) / 256;          // 151 scan tiles (<= 256)
  int gridRows = (n + 3) / 4;         // 12500 mm64 / gather blocks

  // mm64 chunk split across the 4 preproc dispatches (~body-time ratio)
  int C1 = gridRows * 28 / 100;
  int C2 = gridRows * 12 / 100;
  int C3 = gridRows * 26 / 100;
  int C4 = gridRows - C1 - C2 - C3;

  float* ws = (float*)d_ws;
  size_t nf = (size_t)n * 64;
  float* bufA = ws;                   // h1, then h2'
  float* bufB = ws + nf;              // pre-BN h
  float* dinv = ws + 2 * nf;          // n floats
  float* ss = dinv + n;               // 128
  int* rowptr = (int*)(ss + 128);     // n+1
  int* col = rowptr + n + 1;          // E
  int* part = col + E;                // E
  int* hist = part + E;               // S+1
  int* bsum = hist + S + 1;           // nbt (<=256)
  // 16B-align the zero region (float4 stores in fatA)
  float* bnsR = (float*)(((uintptr_t)(bsum + 256) + 15) & ~(uintptr_t)15);  // 256*128
  float* poolR = bnsR + 256 * 128;    // 16*4096
  int* cntR = (int*)(poolR + 16 * 4096);  // CNTB*64 (full overwrite, no zero)

  float* out = (float*)d_out;  // FLOAT32 output

  int blk = 256;

  fatA_kernel<<<nblkP + CNTB + ZBLK + C1, blk, 0, stream>>>(
      dstp, batch, hist, cntR, bnsR, x, W1, bufA, E, n, nblkP, nbuck, 0);
  fatB_kernel<<<nbt + C2, blk, 0, stream>>>(hist, hist, bsum, x, W1, bufA, S, n, nbt, C1);
  fatC_kernel<<<nblkP + C3, blk, 0, stream>>>(srcp, dstp, hist, bsum, part, x, W1, bufA,
                                              E, n, nblkP, nbuck, nbt, C1 + C2);
  fatD_kernel<<<nbuck + C4, blk, 0, stream>>>(part, hist, bsum, rowptr, dinv, col,
                                              x, W1, bufA, n, nblkP, nbuck, nbt, S,
                                              C1 + C2 + C3);

  gather_bn_kernel<<<gridRows, blk, 0, stream>>>(rowptr, col, dinv, bufA, b1, bufB, bnsR, n);
  bn_final_kernel<<<1, 128, 0, stream>>>(bnsR, gamma, beta, ss, n);
  bn_elu_mm64_kernel<<<gridRows, blk, 0, stream>>>(bufB, W2, ss, bufA, n);
  gather_pool_kernel<<<gridRows, blk, 0, stream>>>(rowptr, col, dinv, bufA, b2, out, batch,
                                                   poolR, n);
  pool_final_kernel<<<16, blk, 0, stream>>>(poolR, cntR, out + nf);
}